// Round 6
// baseline (463.030 us; speedup 1.0000x reference)
//
#include <hip/hip_runtime.h>

typedef __bf16 bf16_t;
typedef __bf16 bf16x4 __attribute__((ext_vector_type(4)));
typedef __bf16 bf16x8 __attribute__((ext_vector_type(8)));
typedef float f32x4 __attribute__((ext_vector_type(4)));

__device__ __forceinline__ void load_lds16(const void* g, void* l) {
    __builtin_amdgcn_global_load_lds((const __attribute__((address_space(1))) void*)g,
                                     (__attribute__((address_space(3))) void*)l, 16, 0, 0);
}

// ---------------- fp32 -> bf16 converts (7 tensors, one launch) ----------------
__global__ void cvt_all_k(const float* __restrict__ q, const float* __restrict__ k,
                          const float* __restrict__ v, const float* __restrict__ wq,
                          const float* __restrict__ wk, const float* __restrict__ wv,
                          const float* __restrict__ wo,
                          bf16_t* __restrict__ oq, bf16_t* __restrict__ ok,
                          bf16_t* __restrict__ ov, bf16_t* __restrict__ owq,
                          bf16_t* __restrict__ owk, bf16_t* __restrict__ owv,
                          bf16_t* __restrict__ owo) {
    int y = blockIdx.y;
    int n = (y < 3) ? 4194304 : 1048576;
    int i = (blockIdx.x * 256 + threadIdx.x) * 4;
    if (i >= n) return;
    const float* s;
    bf16_t* d;
    switch (y) {
        case 0: s = q;  d = oq;  break;
        case 1: s = k;  d = ok;  break;
        case 2: s = v;  d = ov;  break;
        case 3: s = wq; d = owq; break;
        case 4: s = wk; d = owk; break;
        case 5: s = wv; d = owv; break;
        default: s = wo; d = owo; break;
    }
    f32x4 t = *reinterpret_cast<const f32x4*>(s + i);
    *reinterpret_cast<bf16x4*>(d + i) = __builtin_convertvector(t, bf16x4);
}

// ---------------- mask -> bitmask ----------------
__global__ void pack_mask_k(const int* __restrict__ mask, unsigned long long* __restrict__ bits) {
    int e = blockIdx.x * blockDim.x + threadIdx.x;
    unsigned long long b = __ballot(mask[e] != 0);
    if ((threadIdx.x & 63) == 0) bits[e >> 6] = b;
}

// ---------------- QKV projection GEMM (3-in-1): C = A @ W^T + bias ----------------
// z=0: Q -> (b,h,s,dh); z=1: K -> (b,h,s,dh); z=2: V -> (b,h,dh,s) transposed
__global__ __launch_bounds__(256, 3) void gemm_qkv(
    const bf16_t* __restrict__ qb, const bf16_t* __restrict__ kb, const bf16_t* __restrict__ vb,
    const bf16_t* __restrict__ wq, const bf16_t* __restrict__ wk, const bf16_t* __restrict__ wv_,
    const float* __restrict__ bq, const float* __restrict__ bk, const float* __restrict__ bv,
    bf16_t* __restrict__ Qh, bf16_t* __restrict__ Kh, bf16_t* __restrict__ Vt)
{
    const int z = blockIdx.z;
    const bf16_t* A = (z == 0) ? qb : (z == 1) ? kb : vb;
    const bf16_t* W = (z == 0) ? wq : (z == 1) ? wk : wv_;
    const float* bias = (z == 0) ? bq : (z == 1) ? bk : bv;
    bf16_t* obf = (z == 0) ? Qh : (z == 1) ? Kh : Vt;

    __shared__ bf16_t As[128 * 64];
    __shared__ bf16_t Bs[128 * 64];
    const int tid = threadIdx.x;
    const int lane = tid & 63;
    const int wv = tid >> 6;
    const int wr = wv >> 1, wc = wv & 1;
    const int la = lane & 15, lb = lane >> 4;
    const int bRow = blockIdx.x, bCol = blockIdx.y;
    f32x4 acc[4][4] = {};

    for (int k0 = 0; k0 < 1024; k0 += 64) {
        __syncthreads();
        for (int i = 0; i < 4; ++i) {
            int o = i * 4096 + tid * 16;
            int row = o >> 7;
            int cb = (o & 127) ^ ((row & 7) << 4);
            const char* sa = (const char*)A + (((size_t)(bRow * 128 + row)) * 1024 + k0) * 2 + cb;
            load_lds16(sa, (char*)As + i * 4096 + wv * 1024);
            const char* sb = (const char*)W + (((size_t)(bCol * 128 + row)) * 1024 + k0) * 2 + cb;
            load_lds16(sb, (char*)Bs + i * 4096 + wv * 1024);
        }
        __syncthreads();

        bf16x8 af[2][4], bfr[2][4];
        for (int mi = 0; mi < 4; ++mi) {
            int row = wr * 64 + mi * 16 + la;
            const char* base = (const char*)As + row * 128;
            int sw = (row & 7) << 4;
            af[0][mi] = *reinterpret_cast<const bf16x8*>(base + ((lb * 16) ^ sw));
            af[1][mi] = *reinterpret_cast<const bf16x8*>(base + ((64 + lb * 16) ^ sw));
        }
        for (int ni = 0; ni < 4; ++ni) {
            int row = wc * 64 + ni * 16 + la;
            const char* base = (const char*)Bs + row * 128;
            int sw = (row & 7) << 4;
            bfr[0][ni] = *reinterpret_cast<const bf16x8*>(base + ((lb * 16) ^ sw));
            bfr[1][ni] = *reinterpret_cast<const bf16x8*>(base + ((64 + lb * 16) ^ sw));
        }
        for (int kk = 0; kk < 2; ++kk)
            for (int mi = 0; mi < 4; ++mi)
                for (int ni = 0; ni < 4; ++ni)
                    acc[mi][ni] = __builtin_amdgcn_mfma_f32_16x16x32_bf16(
                        af[kk][mi], bfr[kk][ni], acc[mi][ni], 0, 0, 0);
    }

    for (int ni = 0; ni < 4; ++ni) {
        int colo = bCol * 128 + wc * 64 + ni * 16 + la;
        float bvv = bias[colo];
        int h = colo >> 6, d = colo & 63;
        for (int mi = 0; mi < 4; ++mi) {
            int n0 = bRow * 128 + wr * 64 + mi * 16 + lb * 4;
            int b_ = n0 >> 11, s0 = n0 & 2047;
            if (z < 2) {
                for (int r = 0; r < 4; ++r) {
                    float v = acc[mi][ni][r] + bvv;
                    obf[(((size_t)(b_ * 16 + h) * 2048 + (s0 + r)) << 6) + d] = (bf16_t)v;
                }
            } else {
                f32x4 vv = acc[mi][ni];
                vv[0] += bvv; vv[1] += bvv; vv[2] += bvv; vv[3] += bvv;
                bf16x4 v4 = __builtin_convertvector(vv, bf16x4);
                *reinterpret_cast<bf16x4*>(
                    &obf[((size_t)(b_ * 16 + h) * 64 + d) * 2048 + s0]) = v4;
            }
        }
    }
}

// ---------------- output projection GEMM: out = attn @ Wo^T + bo (fp32 out) ----------------
__global__ __launch_bounds__(256, 3) void gemm_out(
    const bf16_t* __restrict__ A, const bf16_t* __restrict__ W,
    const float* __restrict__ bias, float* __restrict__ ofp)
{
    __shared__ bf16_t As[128 * 64];
    __shared__ bf16_t Bs[128 * 64];
    const int tid = threadIdx.x;
    const int lane = tid & 63;
    const int wv = tid >> 6;
    const int wr = wv >> 1, wc = wv & 1;
    const int la = lane & 15, lb = lane >> 4;
    const int bRow = blockIdx.x, bCol = blockIdx.y;
    f32x4 acc[4][4] = {};

    for (int k0 = 0; k0 < 1024; k0 += 64) {
        __syncthreads();
        for (int i = 0; i < 4; ++i) {
            int o = i * 4096 + tid * 16;
            int row = o >> 7;
            int cb = (o & 127) ^ ((row & 7) << 4);
            const char* sa = (const char*)A + (((size_t)(bRow * 128 + row)) * 1024 + k0) * 2 + cb;
            load_lds16(sa, (char*)As + i * 4096 + wv * 1024);
            const char* sb = (const char*)W + (((size_t)(bCol * 128 + row)) * 1024 + k0) * 2 + cb;
            load_lds16(sb, (char*)Bs + i * 4096 + wv * 1024);
        }
        __syncthreads();

        bf16x8 af[2][4], bfr[2][4];
        for (int mi = 0; mi < 4; ++mi) {
            int row = wr * 64 + mi * 16 + la;
            const char* base = (const char*)As + row * 128;
            int sw = (row & 7) << 4;
            af[0][mi] = *reinterpret_cast<const bf16x8*>(base + ((lb * 16) ^ sw));
            af[1][mi] = *reinterpret_cast<const bf16x8*>(base + ((64 + lb * 16) ^ sw));
        }
        for (int ni = 0; ni < 4; ++ni) {
            int row = wc * 64 + ni * 16 + la;
            const char* base = (const char*)Bs + row * 128;
            int sw = (row & 7) << 4;
            bfr[0][ni] = *reinterpret_cast<const bf16x8*>(base + ((lb * 16) ^ sw));
            bfr[1][ni] = *reinterpret_cast<const bf16x8*>(base + ((64 + lb * 16) ^ sw));
        }
        for (int kk = 0; kk < 2; ++kk)
            for (int mi = 0; mi < 4; ++mi)
                for (int ni = 0; ni < 4; ++ni)
                    acc[mi][ni] = __builtin_amdgcn_mfma_f32_16x16x32_bf16(
                        af[kk][mi], bfr[kk][ni], acc[mi][ni], 0, 0, 0);
    }

    for (int ni = 0; ni < 4; ++ni) {
        int colo = bCol * 128 + wc * 64 + ni * 16 + la;
        float bvv = bias[colo];
        for (int mi = 0; mi < 4; ++mi)
            for (int r = 0; r < 4; ++r) {
                int n = bRow * 128 + wr * 64 + mi * 16 + lb * 4 + r;
                __builtin_nontemporal_store(acc[mi][ni][r] + bvv,
                                            &ofp[(size_t)n * 1024 + colo]);
            }
    }
}

// ---------------- fused scores + softmax + PV (barrier-free) ----------------
// grid 512 blocks (XCD-swizzled, 2 blocks/CU); block 512 = 8 INDEPENDENT waves,
// each owning 16 q-rows. K is read directly from L2 (256 KB/head, resident:
// m169 lesson — LDS-staging L2-fit data is pure overhead). No __syncthreads at
// all. Swapped-operand QK^T: lane holds (kv=lg*4+r, q=la). No max-subtraction
// (logits bounded ~|3|).
__global__ __launch_bounds__(512, 4) void attn_fused_k(
    const bf16_t* __restrict__ Qh, const bf16_t* __restrict__ Kh,
    const bf16_t* __restrict__ Vt, const unsigned int* __restrict__ mbits,
    float* __restrict__ P, bf16_t* __restrict__ attn)
{
    __shared__ bf16_t Pb[8][16 * 128];  // 8 waves x 4 KB bf16 P chunk (per-wave!)

    // XCD-bijective swizzle: 512 = 8 XCDs x 64 -> each XCD owns 4 heads
    const int wg = blockIdx.x;
    const int swg = (wg & 7) * 64 + (wg >> 3);
    const int bh = swg >> 4, qs = swg & 15;

    const int tid = threadIdx.x, lane = tid & 63, wv = tid >> 6;  // 8 waves
    const int la = lane & 15, lg = lane >> 4;
    const int b_ = bh >> 4;
    const int qbase = qs * 128 + wv * 16;
    const int swz = (la & 7) << 4;

    bf16x8 qf0, qf1;
    {
        const bf16_t* qrow = Qh + ((size_t)bh * 2048 + qbase + la) * 64 + lg * 8;
        qf0 = *reinterpret_cast<const bf16x8*>(qrow);
        qf1 = *reinterpret_cast<const bf16x8*>(qrow + 32);
    }
    const char* Khb = (const char*)(Kh + ((size_t)bh << 17));
    const bf16_t* Vtb = Vt + ((size_t)bh << 17);
    const unsigned int* mrow = mbits + ((size_t)b_ * 2048 + qbase + la) * 64;
    const float SC = 0.125f * 1.4426950408889634f;

    // ---- pass 1: row sums of exp2(logit); K direct from L2, no barriers ----
    float ssum = 0.f;
    for (int c = 0; c < 16; ++c) {
        uint4 mws = *reinterpret_cast<const uint4*>(mrow + c * 4);
        unsigned mwarr[4] = {mws.x, mws.y, mws.z, mws.w};
#pragma unroll
        for (int ct = 0; ct < 8; ++ct) {
            const char* kb = Khb + (size_t)(c * 128 + ct * 16 + la) * 128 + lg * 16;
            bf16x8 kf0 = *reinterpret_cast<const bf16x8*>(kb);
            bf16x8 kf1 = *reinterpret_cast<const bf16x8*>(kb + 64);
            f32x4 acc = {};
            acc = __builtin_amdgcn_mfma_f32_16x16x32_bf16(kf0, qf0, acc, 0, 0, 0);
            acc = __builtin_amdgcn_mfma_f32_16x16x32_bf16(kf1, qf1, acc, 0, 0, 0);
            unsigned mw = mwarr[ct >> 1];
            int shift = ((ct & 1) << 4) + lg * 4;
            for (int r = 0; r < 4; ++r) {
                float t = __builtin_amdgcn_exp2f(acc[r] * SC);
                ssum += ((mw >> (shift + r)) & 1u) ? t : 0.f;
            }
        }
    }
    // reduce over the 4 lg groups (each lane's q-row = la)
    ssum += __shfl_xor(ssum, 16, 64);
    ssum += __shfl_xor(ssum, 32, 64);
    // v_log_f32 IS log2 -> exp2(x*SC - log2(ssum)) = exp2(x*SC)/ssum
    const float nls = -__builtin_amdgcn_logf(ssum);

    // ---- pass 2: recompute, folded-norm exp2, NT P store, PV; no barriers ----
    f32x4 accpv[4] = {};
    float* Pq = P + ((size_t)bh << 22) + (size_t)(qbase + la) * 2048;
    char* Pw = (char*)Pb[wv];
    for (int c = 0; c < 16; ++c) {
        uint4 mws = *reinterpret_cast<const uint4*>(mrow + c * 4);
        unsigned mwarr[4] = {mws.x, mws.y, mws.z, mws.w};
#pragma unroll
        for (int ct = 0; ct < 8; ++ct) {
            const char* kb = Khb + (size_t)(c * 128 + ct * 16 + la) * 128 + lg * 16;
            bf16x8 kf0 = *reinterpret_cast<const bf16x8*>(kb);
            bf16x8 kf1 = *reinterpret_cast<const bf16x8*>(kb + 64);
            f32x4 acc = {};
            acc = __builtin_amdgcn_mfma_f32_16x16x32_bf16(kf0, qf0, acc, 0, 0, 0);
            acc = __builtin_amdgcn_mfma_f32_16x16x32_bf16(kf1, qf1, acc, 0, 0, 0);
            unsigned mw = mwarr[ct >> 1];
            int shift = ((ct & 1) << 4) + lg * 4;
            f32x4 pv;
            for (int r = 0; r < 4; ++r) {
                float t = __builtin_amdgcn_exp2f(__builtin_fmaf(acc[r], SC, nls));
                pv[r] = ((mw >> (shift + r)) & 1u) ? t : 0.f;
            }
            __builtin_nontemporal_store(
                pv, reinterpret_cast<f32x4*>(Pq + c * 128 + ct * 16 + lg * 4));
            bf16x4 pb4 = __builtin_convertvector(pv, bf16x4);
            *reinterpret_cast<bf16x4*>(Pw + ((la * 256 + ct * 32 + lg * 8) ^ swz)) = pb4;
        }
        // per-wave: ensure own Pb writes landed before reading A-fragments
        asm volatile("s_waitcnt lgkmcnt(0)" ::: "memory");
        __builtin_amdgcn_sched_barrier(0);
        for (int kbk = 0; kbk < 4; ++kbk) {
            bf16x8 pa = *reinterpret_cast<const bf16x8*>(
                Pw + ((la * 256 + kbk * 64 + lg * 16) ^ swz));
            const bf16_t* vb2 = Vtb + c * 128 + kbk * 32 + lg * 8;
            for (int ni = 0; ni < 4; ++ni) {
                bf16x8 vf = *reinterpret_cast<const bf16x8*>(vb2 + (size_t)(ni * 16 + la) * 2048);
                accpv[ni] = __builtin_amdgcn_mfma_f32_16x16x32_bf16(pa, vf, accpv[ni], 0, 0, 0);
            }
        }
    }

    bf16_t* ab = attn + ((size_t)bh << 17);
    for (int ni = 0; ni < 4; ++ni)
        for (int r = 0; r < 4; ++r)
            ab[(size_t)(qbase + lg * 4 + r) * 64 + ni * 16 + la] = (bf16_t)accpv[ni][r];
}

extern "C" void kernel_launch(void* const* d_in, const int* in_sizes, int n_in,
                              void* d_out, int out_size, void* d_ws, size_t ws_size,
                              hipStream_t stream) {
    const float* q  = (const float*)d_in[0];
    const float* k  = (const float*)d_in[1];
    const float* v  = (const float*)d_in[2];
    const int* mask = (const int*)d_in[3];
    const float* Wq = (const float*)d_in[4];
    const float* bq = (const float*)d_in[5];
    const float* Wk = (const float*)d_in[6];
    const float* bk = (const float*)d_in[7];
    const float* Wv = (const float*)d_in[8];
    const float* bv = (const float*)d_in[9];
    const float* Wo = (const float*)d_in[10];
    const float* bo = (const float*)d_in[11];

    char* ws = (char*)d_ws;
    bf16_t* qb    = (bf16_t*)(ws + 0);
    bf16_t* kb    = (bf16_t*)(ws + 8388608);
    bf16_t* vb    = (bf16_t*)(ws + 16777216);
    bf16_t* wqb   = (bf16_t*)(ws + 25165824);
    bf16_t* wkb   = (bf16_t*)(ws + 27262976);
    bf16_t* wvb   = (bf16_t*)(ws + 29360128);
    bf16_t* wob   = (bf16_t*)(ws + 31457280);
    bf16_t* Qh    = (bf16_t*)(ws + 33554432);
    bf16_t* Kh    = (bf16_t*)(ws + 41943040);
    bf16_t* Vt    = (bf16_t*)(ws + 50331648);
    bf16_t* attnb = (bf16_t*)(ws + 58720256);
    unsigned long long* mbits = (unsigned long long*)(ws + 67108864);

    float* out   = (float*)d_out;
    float* score = out + 4194304;

    cvt_all_k<<<dim3(4096, 7), 256, 0, stream>>>(q, k, v, Wq, Wk, Wv, Wo,
                                                 qb, kb, vb, wqb, wkb, wvb, wob);
    pack_mask_k<<<32768, 256, 0, stream>>>(mask, mbits);

    gemm_qkv<<<dim3(32, 8, 3), 256, 0, stream>>>(qb, kb, vb, wqb, wkb, wvb,
                                                 bq, bk, bv, Qh, Kh, Vt);

    attn_fused_k<<<512, 512, 0, stream>>>(Qh, Kh, Vt, (const unsigned int*)mbits,
                                          score, attnb);

    gemm_out<<<dim3(32, 8), 256, 0, stream>>>(attnb, wob, bo, out);
}

// Round 7
// 348.433 us; speedup vs baseline: 1.3289x; 1.3289x over previous
//
#include <hip/hip_runtime.h>

typedef __bf16 bf16_t;
typedef __bf16 bf16x4 __attribute__((ext_vector_type(4)));
typedef __bf16 bf16x8 __attribute__((ext_vector_type(8)));
typedef float f32x4 __attribute__((ext_vector_type(4)));

__device__ __forceinline__ void load_lds16(const void* g, void* l) {
    __builtin_amdgcn_global_load_lds((const __attribute__((address_space(1))) void*)g,
                                     (__attribute__((address_space(3))) void*)l, 16, 0, 0);
}

// ---------------- fp32 -> bf16 converts (7 tensors, one launch) ----------------
__global__ void cvt_all_k(const float* __restrict__ q, const float* __restrict__ k,
                          const float* __restrict__ v, const float* __restrict__ wq,
                          const float* __restrict__ wk, const float* __restrict__ wv,
                          const float* __restrict__ wo,
                          bf16_t* __restrict__ oq, bf16_t* __restrict__ ok,
                          bf16_t* __restrict__ ov, bf16_t* __restrict__ owq,
                          bf16_t* __restrict__ owk, bf16_t* __restrict__ owv,
                          bf16_t* __restrict__ owo) {
    int y = blockIdx.y;
    int n = (y < 3) ? 4194304 : 1048576;
    int i = (blockIdx.x * 256 + threadIdx.x) * 4;
    if (i >= n) return;
    const float* s;
    bf16_t* d;
    switch (y) {
        case 0: s = q;  d = oq;  break;
        case 1: s = k;  d = ok;  break;
        case 2: s = v;  d = ov;  break;
        case 3: s = wq; d = owq; break;
        case 4: s = wk; d = owk; break;
        case 5: s = wv; d = owv; break;
        default: s = wo; d = owo; break;
    }
    f32x4 t = *reinterpret_cast<const f32x4*>(s + i);
    *reinterpret_cast<bf16x4*>(d + i) = __builtin_convertvector(t, bf16x4);
}

// ---------------- mask -> bitmask ----------------
__global__ void pack_mask_k(const int* __restrict__ mask, unsigned long long* __restrict__ bits) {
    int e = blockIdx.x * blockDim.x + threadIdx.x;
    unsigned long long b = __ballot(mask[e] != 0);
    if ((threadIdx.x & 63) == 0) bits[e >> 6] = b;
}

// ---------------- QKV projection GEMM (3-in-1): C = A @ W^T + bias ----------------
// z=0: Q -> (b,h,s,dh); z=1: K -> (b,h,s,dh); z=2: V -> (b,h,dh,s) transposed
__global__ __launch_bounds__(256, 3) void gemm_qkv(
    const bf16_t* __restrict__ qb, const bf16_t* __restrict__ kb, const bf16_t* __restrict__ vb,
    const bf16_t* __restrict__ wq, const bf16_t* __restrict__ wk, const bf16_t* __restrict__ wv_,
    const float* __restrict__ bq, const float* __restrict__ bk, const float* __restrict__ bv,
    bf16_t* __restrict__ Qh, bf16_t* __restrict__ Kh, bf16_t* __restrict__ Vt)
{
    const int z = blockIdx.z;
    const bf16_t* A = (z == 0) ? qb : (z == 1) ? kb : vb;
    const bf16_t* W = (z == 0) ? wq : (z == 1) ? wk : wv_;
    const float* bias = (z == 0) ? bq : (z == 1) ? bk : bv;
    bf16_t* obf = (z == 0) ? Qh : (z == 1) ? Kh : Vt;

    __shared__ bf16_t As[128 * 64];
    __shared__ bf16_t Bs[128 * 64];
    const int tid = threadIdx.x;
    const int lane = tid & 63;
    const int wv = tid >> 6;
    const int wr = wv >> 1, wc = wv & 1;
    const int la = lane & 15, lb = lane >> 4;
    const int bRow = blockIdx.x, bCol = blockIdx.y;
    f32x4 acc[4][4] = {};

    for (int k0 = 0; k0 < 1024; k0 += 64) {
        __syncthreads();
        for (int i = 0; i < 4; ++i) {
            int o = i * 4096 + tid * 16;
            int row = o >> 7;
            int cb = (o & 127) ^ ((row & 7) << 4);
            const char* sa = (const char*)A + (((size_t)(bRow * 128 + row)) * 1024 + k0) * 2 + cb;
            load_lds16(sa, (char*)As + i * 4096 + wv * 1024);
            const char* sb = (const char*)W + (((size_t)(bCol * 128 + row)) * 1024 + k0) * 2 + cb;
            load_lds16(sb, (char*)Bs + i * 4096 + wv * 1024);
        }
        __syncthreads();

        bf16x8 af[2][4], bfr[2][4];
        for (int mi = 0; mi < 4; ++mi) {
            int row = wr * 64 + mi * 16 + la;
            const char* base = (const char*)As + row * 128;
            int sw = (row & 7) << 4;
            af[0][mi] = *reinterpret_cast<const bf16x8*>(base + ((lb * 16) ^ sw));
            af[1][mi] = *reinterpret_cast<const bf16x8*>(base + ((64 + lb * 16) ^ sw));
        }
        for (int ni = 0; ni < 4; ++ni) {
            int row = wc * 64 + ni * 16 + la;
            const char* base = (const char*)Bs + row * 128;
            int sw = (row & 7) << 4;
            bfr[0][ni] = *reinterpret_cast<const bf16x8*>(base + ((lb * 16) ^ sw));
            bfr[1][ni] = *reinterpret_cast<const bf16x8*>(base + ((64 + lb * 16) ^ sw));
        }
        for (int kk = 0; kk < 2; ++kk)
            for (int mi = 0; mi < 4; ++mi)
                for (int ni = 0; ni < 4; ++ni)
                    acc[mi][ni] = __builtin_amdgcn_mfma_f32_16x16x32_bf16(
                        af[kk][mi], bfr[kk][ni], acc[mi][ni], 0, 0, 0);
    }

    for (int ni = 0; ni < 4; ++ni) {
        int colo = bCol * 128 + wc * 64 + ni * 16 + la;
        float bvv = bias[colo];
        int h = colo >> 6, d = colo & 63;
        for (int mi = 0; mi < 4; ++mi) {
            int n0 = bRow * 128 + wr * 64 + mi * 16 + lb * 4;
            int b_ = n0 >> 11, s0 = n0 & 2047;
            if (z < 2) {
                for (int r = 0; r < 4; ++r) {
                    float v = acc[mi][ni][r] + bvv;
                    obf[(((size_t)(b_ * 16 + h) * 2048 + (s0 + r)) << 6) + d] = (bf16_t)v;
                }
            } else {
                f32x4 vv = acc[mi][ni];
                vv[0] += bvv; vv[1] += bvv; vv[2] += bvv; vv[3] += bvv;
                bf16x4 v4 = __builtin_convertvector(vv, bf16x4);
                *reinterpret_cast<bf16x4*>(
                    &obf[((size_t)(b_ * 16 + h) * 64 + d) * 2048 + s0]) = v4;
            }
        }
    }
}

// ---------------- output projection GEMM: out = attn @ Wo^T + bo (fp32 out) ----------------
__global__ __launch_bounds__(256, 3) void gemm_out(
    const bf16_t* __restrict__ A, const bf16_t* __restrict__ W,
    const float* __restrict__ bias, float* __restrict__ ofp)
{
    __shared__ bf16_t As[128 * 64];
    __shared__ bf16_t Bs[128 * 64];
    const int tid = threadIdx.x;
    const int lane = tid & 63;
    const int wv = tid >> 6;
    const int wr = wv >> 1, wc = wv & 1;
    const int la = lane & 15, lb = lane >> 4;
    const int bRow = blockIdx.x, bCol = blockIdx.y;
    f32x4 acc[4][4] = {};

    for (int k0 = 0; k0 < 1024; k0 += 64) {
        __syncthreads();
        for (int i = 0; i < 4; ++i) {
            int o = i * 4096 + tid * 16;
            int row = o >> 7;
            int cb = (o & 127) ^ ((row & 7) << 4);
            const char* sa = (const char*)A + (((size_t)(bRow * 128 + row)) * 1024 + k0) * 2 + cb;
            load_lds16(sa, (char*)As + i * 4096 + wv * 1024);
            const char* sb = (const char*)W + (((size_t)(bCol * 128 + row)) * 1024 + k0) * 2 + cb;
            load_lds16(sb, (char*)Bs + i * 4096 + wv * 1024);
        }
        __syncthreads();

        bf16x8 af[2][4], bfr[2][4];
        for (int mi = 0; mi < 4; ++mi) {
            int row = wr * 64 + mi * 16 + la;
            const char* base = (const char*)As + row * 128;
            int sw = (row & 7) << 4;
            af[0][mi] = *reinterpret_cast<const bf16x8*>(base + ((lb * 16) ^ sw));
            af[1][mi] = *reinterpret_cast<const bf16x8*>(base + ((64 + lb * 16) ^ sw));
        }
        for (int ni = 0; ni < 4; ++ni) {
            int row = wc * 64 + ni * 16 + la;
            const char* base = (const char*)Bs + row * 128;
            int sw = (row & 7) << 4;
            bfr[0][ni] = *reinterpret_cast<const bf16x8*>(base + ((lb * 16) ^ sw));
            bfr[1][ni] = *reinterpret_cast<const bf16x8*>(base + ((64 + lb * 16) ^ sw));
        }
        for (int kk = 0; kk < 2; ++kk)
            for (int mi = 0; mi < 4; ++mi)
                for (int ni = 0; ni < 4; ++ni)
                    acc[mi][ni] = __builtin_amdgcn_mfma_f32_16x16x32_bf16(
                        af[kk][mi], bfr[kk][ni], acc[mi][ni], 0, 0, 0);
    }

    for (int ni = 0; ni < 4; ++ni) {
        int colo = bCol * 128 + wc * 64 + ni * 16 + la;
        float bvv = bias[colo];
        for (int mi = 0; mi < 4; ++mi)
            for (int r = 0; r < 4; ++r) {
                int n = bRow * 128 + wr * 64 + mi * 16 + lb * 4 + r;
                __builtin_nontemporal_store(acc[mi][ni][r] + bvv,
                                            &ofp[(size_t)n * 1024 + colo]);
            }
    }
}

// ---------------- fused scores + softmax + PV ----------------
// grid 512 blocks (XCD-swizzled, 2 blocks/CU); block 512 = 8 waves x 16 q-rows.
// 2048 kv in 16 double-buffered 128-kv chunks (global_load_lds dbuf = the
// latency-hiding mechanism; R6 proved direct L2 reads are latency-bound).
// Swapped-operand QK^T: lane holds (kv=lg*4+r, q=la). No max-subtraction
// (logits bounded ~|3|). P stores are PLAIN (not NT): R6 counters showed NT
// 16B/lane stores amplify writes 1.37x (725 vs 528 MiB).
__global__ __launch_bounds__(512, 4) void attn_fused_k(
    const bf16_t* __restrict__ Qh, const bf16_t* __restrict__ Kh,
    const bf16_t* __restrict__ Vt, const unsigned int* __restrict__ mbits,
    float* __restrict__ P, bf16_t* __restrict__ attn)
{
    __shared__ bf16_t Ks[2][128 * 64];  // 2 x 16 KB swizzled K chunks (dbuf)
    __shared__ bf16_t Pb[8][16 * 128];  // 8 waves x 4 KB bf16 P chunk

    // XCD-bijective swizzle: 512 = 8 XCDs x 64 -> each XCD owns 4 heads
    const int wg = blockIdx.x;
    const int swg = (wg & 7) * 64 + (wg >> 3);
    const int bh = swg >> 4, qs = swg & 15;

    const int tid = threadIdx.x, lane = tid & 63, wv = tid >> 6;  // 8 waves
    const int la = lane & 15, lg = lane >> 4;
    const int b_ = bh >> 4;
    const int qbase = qs * 128 + wv * 16;
    const int swz = (la & 7) << 4;

    bf16x8 qf0, qf1;
    {
        const bf16_t* qrow = Qh + ((size_t)bh * 2048 + qbase + la) * 64 + lg * 8;
        qf0 = *reinterpret_cast<const bf16x8*>(qrow);
        qf1 = *reinterpret_cast<const bf16x8*>(qrow + 32);
    }
    const char* Khb = (const char*)(Kh + ((size_t)bh << 17));
    const bf16_t* Vtb = Vt + ((size_t)bh << 17);
    const unsigned int* mrow = mbits + ((size_t)b_ * 2048 + qbase + la) * 64;
    const float SC = 0.125f * 1.4426950408889634f;

#define STAGE_K(c, bsel)                                                      \
    for (int i = 0; i < 2; ++i) {                                             \
        int o = i * 8192 + tid * 16;                                          \
        int row = o >> 7;                                                     \
        int cb = (o & 127) ^ ((row & 7) << 4);                                \
        load_lds16(Khb + (size_t)(c) * 16384 + row * 128 + cb,                \
                   (char*)Ks[bsel] + i * 8192 + wv * 1024);                   \
    }

    // ---- pass 1: row sums of exp2(logit) ----
    float ssum = 0.f;
    uint4 mws = *reinterpret_cast<const uint4*>(mrow);
    STAGE_K(0, 0)
    __syncthreads();
    for (int c = 0; c < 16; ++c) {
        int cn = (c < 15) ? c + 1 : 15;
        uint4 mnext = *reinterpret_cast<const uint4*>(mrow + cn * 4);  // prefetch
        if (c < 15) { STAGE_K(c + 1, (c + 1) & 1) }
        __builtin_amdgcn_sched_barrier(0);
        const char* Kbase = (const char*)Ks[c & 1];
        unsigned mwarr[4] = {mws.x, mws.y, mws.z, mws.w};
        __builtin_amdgcn_s_setprio(1);
#pragma unroll
        for (int ct = 0; ct < 8; ++ct) {
            int krow = ct * 16 + la;
            const char* kb = Kbase + krow * 128;
            int sw = (krow & 7) << 4;
            bf16x8 kf0 = *reinterpret_cast<const bf16x8*>(kb + ((lg * 16) ^ sw));
            bf16x8 kf1 = *reinterpret_cast<const bf16x8*>(kb + ((64 + lg * 16) ^ sw));
            f32x4 acc = {};
            acc = __builtin_amdgcn_mfma_f32_16x16x32_bf16(kf0, qf0, acc, 0, 0, 0);
            acc = __builtin_amdgcn_mfma_f32_16x16x32_bf16(kf1, qf1, acc, 0, 0, 0);
            unsigned mw = mwarr[ct >> 1];
            int shift = ((ct & 1) << 4) + lg * 4;
            for (int r = 0; r < 4; ++r) {
                float t = __builtin_amdgcn_exp2f(acc[r] * SC);
                ssum += ((mw >> (shift + r)) & 1u) ? t : 0.f;
            }
        }
        __builtin_amdgcn_s_setprio(0);
        __syncthreads();
        mws = mnext;
    }
    // reduce over the 4 lg groups (each lane's q-row = la)
    ssum += __shfl_xor(ssum, 16, 64);
    ssum += __shfl_xor(ssum, 32, 64);
    // v_log_f32 IS log2 -> exp2(x*SC - log2(ssum)) = exp2(x*SC)/ssum
    const float nls = -__builtin_amdgcn_logf(ssum);

    // ---- pass 2: recompute, exp2(fma) with folded norm, plain P store, PV ----
    f32x4 accpv[4] = {};
    float* Pq = P + ((size_t)bh << 22) + (size_t)(qbase + la) * 2048;
    char* Pw = (char*)Pb[wv];
    mws = *reinterpret_cast<const uint4*>(mrow);
    STAGE_K(0, 0)
    __syncthreads();
    for (int c = 0; c < 16; ++c) {
        int cn = (c < 15) ? c + 1 : 15;
        uint4 mnext = *reinterpret_cast<const uint4*>(mrow + cn * 4);  // prefetch
        if (c < 15) { STAGE_K(c + 1, (c + 1) & 1) }
        __builtin_amdgcn_sched_barrier(0);
        const char* Kbase = (const char*)Ks[c & 1];
        unsigned mwarr[4] = {mws.x, mws.y, mws.z, mws.w};
        __builtin_amdgcn_s_setprio(1);
#pragma unroll
        for (int ct = 0; ct < 8; ++ct) {
            int krow = ct * 16 + la;
            const char* kb = Kbase + krow * 128;
            int sw = (krow & 7) << 4;
            bf16x8 kf0 = *reinterpret_cast<const bf16x8*>(kb + ((lg * 16) ^ sw));
            bf16x8 kf1 = *reinterpret_cast<const bf16x8*>(kb + ((64 + lg * 16) ^ sw));
            f32x4 acc = {};
            acc = __builtin_amdgcn_mfma_f32_16x16x32_bf16(kf0, qf0, acc, 0, 0, 0);
            acc = __builtin_amdgcn_mfma_f32_16x16x32_bf16(kf1, qf1, acc, 0, 0, 0);
            unsigned mw = mwarr[ct >> 1];
            int shift = ((ct & 1) << 4) + lg * 4;
            f32x4 pv;
            for (int r = 0; r < 4; ++r) {
                float t = __builtin_amdgcn_exp2f(__builtin_fmaf(acc[r], SC, nls));
                pv[r] = ((mw >> (shift + r)) & 1u) ? t : 0.f;
            }
            *reinterpret_cast<f32x4*>(Pq + c * 128 + ct * 16 + lg * 4) = pv;
            bf16x4 pb4 = __builtin_convertvector(pv, bf16x4);
            *reinterpret_cast<bf16x4*>(Pw + ((la * 256 + ct * 32 + lg * 8) ^ swz)) = pb4;
        }
        // per-wave: ensure Pb writes landed before reading A-fragments
        asm volatile("s_waitcnt lgkmcnt(0)" ::: "memory");
        __builtin_amdgcn_sched_barrier(0);
        for (int kbk = 0; kbk < 4; ++kbk) {
            bf16x8 pa = *reinterpret_cast<const bf16x8*>(
                Pw + ((la * 256 + kbk * 64 + lg * 16) ^ swz));
            const bf16_t* vb2 = Vtb + c * 128 + kbk * 32 + lg * 8;
            for (int ni = 0; ni < 4; ++ni) {
                bf16x8 vf = *reinterpret_cast<const bf16x8*>(vb2 + (size_t)(ni * 16 + la) * 2048);
                accpv[ni] = __builtin_amdgcn_mfma_f32_16x16x32_bf16(pa, vf, accpv[ni], 0, 0, 0);
            }
        }
        __builtin_amdgcn_s_setprio(0);
        // counted wait: 2 stage loads of c+1 are older than the <=8 P stores
        asm volatile("s_waitcnt vmcnt(8)" ::: "memory");
        __builtin_amdgcn_s_barrier();
        mws = mnext;
    }
#undef STAGE_K

    bf16_t* ab = attn + ((size_t)bh << 17);
    for (int ni = 0; ni < 4; ++ni)
        for (int r = 0; r < 4; ++r)
            ab[(size_t)(qbase + lg * 4 + r) * 64 + ni * 16 + la] = (bf16_t)accpv[ni][r];
}

extern "C" void kernel_launch(void* const* d_in, const int* in_sizes, int n_in,
                              void* d_out, int out_size, void* d_ws, size_t ws_size,
                              hipStream_t stream) {
    const float* q  = (const float*)d_in[0];
    const float* k  = (const float*)d_in[1];
    const float* v  = (const float*)d_in[2];
    const int* mask = (const int*)d_in[3];
    const float* Wq = (const float*)d_in[4];
    const float* bq = (const float*)d_in[5];
    const float* Wk = (const float*)d_in[6];
    const float* bk = (const float*)d_in[7];
    const float* Wv = (const float*)d_in[8];
    const float* bv = (const float*)d_in[9];
    const float* Wo = (const float*)d_in[10];
    const float* bo = (const float*)d_in[11];

    char* ws = (char*)d_ws;
    bf16_t* qb    = (bf16_t*)(ws + 0);
    bf16_t* kb    = (bf16_t*)(ws + 8388608);
    bf16_t* vb    = (bf16_t*)(ws + 16777216);
    bf16_t* wqb   = (bf16_t*)(ws + 25165824);
    bf16_t* wkb   = (bf16_t*)(ws + 27262976);
    bf16_t* wvb   = (bf16_t*)(ws + 29360128);
    bf16_t* wob   = (bf16_t*)(ws + 31457280);
    bf16_t* Qh    = (bf16_t*)(ws + 33554432);
    bf16_t* Kh    = (bf16_t*)(ws + 41943040);
    bf16_t* Vt    = (bf16_t*)(ws + 50331648);
    bf16_t* attnb = (bf16_t*)(ws + 58720256);
    unsigned long long* mbits = (unsigned long long*)(ws + 67108864);

    float* out   = (float*)d_out;
    float* score = out + 4194304;

    cvt_all_k<<<dim3(4096, 7), 256, 0, stream>>>(q, k, v, Wq, Wk, Wv, Wo,
                                                 qb, kb, vb, wqb, wkb, wvb, wob);
    pack_mask_k<<<32768, 256, 0, stream>>>(mask, mbits);

    gemm_qkv<<<dim3(32, 8, 3), 256, 0, stream>>>(qb, kb, vb, wqb, wkb, wvb,
                                                 bq, bk, bv, Qh, Kh, Vt);

    attn_fused_k<<<512, 512, 0, stream>>>(Qh, Kh, Vt, (const unsigned int*)mbits,
                                          score, attnb);

    gemm_out<<<dim3(32, 8), 256, 0, stream>>>(attnb, wob, bo, out);
}

// Round 8
// 298.038 us; speedup vs baseline: 1.5536x; 1.1691x over previous
//
#include <hip/hip_runtime.h>

typedef __bf16 bf16_t;
typedef __bf16 bf16x4 __attribute__((ext_vector_type(4)));
typedef __bf16 bf16x8 __attribute__((ext_vector_type(8)));
typedef float f32x4 __attribute__((ext_vector_type(4)));

__device__ __forceinline__ void load_lds16(const void* g, void* l) {
    __builtin_amdgcn_global_load_lds((const __attribute__((address_space(1))) void*)g,
                                     (__attribute__((address_space(3))) void*)l, 16, 0, 0);
}

// ---------------- fp32 -> bf16 converts (7 tensors, one launch) ----------------
__global__ void cvt_all_k(const float* __restrict__ q, const float* __restrict__ k,
                          const float* __restrict__ v, const float* __restrict__ wq,
                          const float* __restrict__ wk, const float* __restrict__ wv,
                          const float* __restrict__ wo,
                          bf16_t* __restrict__ oq, bf16_t* __restrict__ ok,
                          bf16_t* __restrict__ ov, bf16_t* __restrict__ owq,
                          bf16_t* __restrict__ owk, bf16_t* __restrict__ owv,
                          bf16_t* __restrict__ owo) {
    int y = blockIdx.y;
    int n = (y < 3) ? 4194304 : 1048576;
    int i = (blockIdx.x * 256 + threadIdx.x) * 4;
    if (i >= n) return;
    const float* s;
    bf16_t* d;
    switch (y) {
        case 0: s = q;  d = oq;  break;
        case 1: s = k;  d = ok;  break;
        case 2: s = v;  d = ov;  break;
        case 3: s = wq; d = owq; break;
        case 4: s = wk; d = owk; break;
        case 5: s = wv; d = owv; break;
        default: s = wo; d = owo; break;
    }
    f32x4 t = *reinterpret_cast<const f32x4*>(s + i);
    *reinterpret_cast<bf16x4*>(d + i) = __builtin_convertvector(t, bf16x4);
}

// ---------------- mask -> bitmask ----------------
__global__ void pack_mask_k(const int* __restrict__ mask, unsigned long long* __restrict__ bits) {
    int e = blockIdx.x * blockDim.x + threadIdx.x;
    unsigned long long b = __ballot(mask[e] != 0);
    if ((threadIdx.x & 63) == 0) bits[e >> 6] = b;
}

// ---------------- QKV projection GEMM (3-in-1): C = A @ W^T + bias ----------------
// z=0: Q -> (b,h,s,dh); z=1: K -> (b,h,s,dh); z=2: V -> (b,h,dh,s) transposed
__global__ __launch_bounds__(256, 3) void gemm_qkv(
    const bf16_t* __restrict__ qb, const bf16_t* __restrict__ kb, const bf16_t* __restrict__ vb,
    const bf16_t* __restrict__ wq, const bf16_t* __restrict__ wk, const bf16_t* __restrict__ wv_,
    const float* __restrict__ bq, const float* __restrict__ bk, const float* __restrict__ bv,
    bf16_t* __restrict__ Qh, bf16_t* __restrict__ Kh, bf16_t* __restrict__ Vt)
{
    const int z = blockIdx.z;
    const bf16_t* A = (z == 0) ? qb : (z == 1) ? kb : vb;
    const bf16_t* W = (z == 0) ? wq : (z == 1) ? wk : wv_;
    const float* bias = (z == 0) ? bq : (z == 1) ? bk : bv;
    bf16_t* obf = (z == 0) ? Qh : (z == 1) ? Kh : Vt;

    __shared__ bf16_t As[128 * 64];
    __shared__ bf16_t Bs[128 * 64];
    const int tid = threadIdx.x;
    const int lane = tid & 63;
    const int wv = tid >> 6;
    const int wr = wv >> 1, wc = wv & 1;
    const int la = lane & 15, lb = lane >> 4;
    const int bRow = blockIdx.x, bCol = blockIdx.y;
    f32x4 acc[4][4] = {};

    for (int k0 = 0; k0 < 1024; k0 += 64) {
        __syncthreads();
        for (int i = 0; i < 4; ++i) {
            int o = i * 4096 + tid * 16;
            int row = o >> 7;
            int cb = (o & 127) ^ ((row & 7) << 4);
            const char* sa = (const char*)A + (((size_t)(bRow * 128 + row)) * 1024 + k0) * 2 + cb;
            load_lds16(sa, (char*)As + i * 4096 + wv * 1024);
            const char* sb = (const char*)W + (((size_t)(bCol * 128 + row)) * 1024 + k0) * 2 + cb;
            load_lds16(sb, (char*)Bs + i * 4096 + wv * 1024);
        }
        __syncthreads();

        bf16x8 af[2][4], bfr[2][4];
        for (int mi = 0; mi < 4; ++mi) {
            int row = wr * 64 + mi * 16 + la;
            const char* base = (const char*)As + row * 128;
            int sw = (row & 7) << 4;
            af[0][mi] = *reinterpret_cast<const bf16x8*>(base + ((lb * 16) ^ sw));
            af[1][mi] = *reinterpret_cast<const bf16x8*>(base + ((64 + lb * 16) ^ sw));
        }
        for (int ni = 0; ni < 4; ++ni) {
            int row = wc * 64 + ni * 16 + la;
            const char* base = (const char*)Bs + row * 128;
            int sw = (row & 7) << 4;
            bfr[0][ni] = *reinterpret_cast<const bf16x8*>(base + ((lb * 16) ^ sw));
            bfr[1][ni] = *reinterpret_cast<const bf16x8*>(base + ((64 + lb * 16) ^ sw));
        }
        for (int kk = 0; kk < 2; ++kk)
            for (int mi = 0; mi < 4; ++mi)
                for (int ni = 0; ni < 4; ++ni)
                    acc[mi][ni] = __builtin_amdgcn_mfma_f32_16x16x32_bf16(
                        af[kk][mi], bfr[kk][ni], acc[mi][ni], 0, 0, 0);
    }

    for (int ni = 0; ni < 4; ++ni) {
        int colo = bCol * 128 + wc * 64 + ni * 16 + la;
        float bvv = bias[colo];
        int h = colo >> 6, d = colo & 63;
        for (int mi = 0; mi < 4; ++mi) {
            int n0 = bRow * 128 + wr * 64 + mi * 16 + lb * 4;
            int b_ = n0 >> 11, s0 = n0 & 2047;
            if (z < 2) {
                for (int r = 0; r < 4; ++r) {
                    float v = acc[mi][ni][r] + bvv;
                    obf[(((size_t)(b_ * 16 + h) * 2048 + (s0 + r)) << 6) + d] = (bf16_t)v;
                }
            } else {
                f32x4 vv = acc[mi][ni];
                vv[0] += bvv; vv[1] += bvv; vv[2] += bvv; vv[3] += bvv;
                bf16x4 v4 = __builtin_convertvector(vv, bf16x4);
                *reinterpret_cast<bf16x4*>(
                    &obf[((size_t)(b_ * 16 + h) * 64 + d) * 2048 + s0]) = v4;
            }
        }
    }
}

// ---------------- output projection GEMM: out = attn @ Wo^T + bo (fp32 out) ----------------
__global__ __launch_bounds__(256, 3) void gemm_out(
    const bf16_t* __restrict__ A, const bf16_t* __restrict__ W,
    const float* __restrict__ bias, float* __restrict__ ofp)
{
    __shared__ bf16_t As[128 * 64];
    __shared__ bf16_t Bs[128 * 64];
    const int tid = threadIdx.x;
    const int lane = tid & 63;
    const int wv = tid >> 6;
    const int wr = wv >> 1, wc = wv & 1;
    const int la = lane & 15, lb = lane >> 4;
    const int bRow = blockIdx.x, bCol = blockIdx.y;
    f32x4 acc[4][4] = {};

    for (int k0 = 0; k0 < 1024; k0 += 64) {
        __syncthreads();
        for (int i = 0; i < 4; ++i) {
            int o = i * 4096 + tid * 16;
            int row = o >> 7;
            int cb = (o & 127) ^ ((row & 7) << 4);
            const char* sa = (const char*)A + (((size_t)(bRow * 128 + row)) * 1024 + k0) * 2 + cb;
            load_lds16(sa, (char*)As + i * 4096 + wv * 1024);
            const char* sb = (const char*)W + (((size_t)(bCol * 128 + row)) * 1024 + k0) * 2 + cb;
            load_lds16(sb, (char*)Bs + i * 4096 + wv * 1024);
        }
        __syncthreads();

        bf16x8 af[2][4], bfr[2][4];
        for (int mi = 0; mi < 4; ++mi) {
            int row = wr * 64 + mi * 16 + la;
            const char* base = (const char*)As + row * 128;
            int sw = (row & 7) << 4;
            af[0][mi] = *reinterpret_cast<const bf16x8*>(base + ((lb * 16) ^ sw));
            af[1][mi] = *reinterpret_cast<const bf16x8*>(base + ((64 + lb * 16) ^ sw));
        }
        for (int ni = 0; ni < 4; ++ni) {
            int row = wc * 64 + ni * 16 + la;
            const char* base = (const char*)Bs + row * 128;
            int sw = (row & 7) << 4;
            bfr[0][ni] = *reinterpret_cast<const bf16x8*>(base + ((lb * 16) ^ sw));
            bfr[1][ni] = *reinterpret_cast<const bf16x8*>(base + ((64 + lb * 16) ^ sw));
        }
        for (int kk = 0; kk < 2; ++kk)
            for (int mi = 0; mi < 4; ++mi)
                for (int ni = 0; ni < 4; ++ni)
                    acc[mi][ni] = __builtin_amdgcn_mfma_f32_16x16x32_bf16(
                        af[kk][mi], bfr[kk][ni], acc[mi][ni], 0, 0, 0);
    }

    for (int ni = 0; ni < 4; ++ni) {
        int colo = bCol * 128 + wc * 64 + ni * 16 + la;
        float bvv = bias[colo];
        for (int mi = 0; mi < 4; ++mi)
            for (int r = 0; r < 4; ++r) {
                int n = bRow * 128 + wr * 64 + mi * 16 + lb * 4 + r;
                __builtin_nontemporal_store(acc[mi][ni][r] + bvv,
                                            &ofp[(size_t)n * 1024 + colo]);
            }
    }
}

// ---------------- fused scores + softmax + PV ----------------
// grid 512 blocks (XCD-swizzled, 2 blocks/CU); block 512 = 8 waves x 16 q-rows.
// 2048 kv in 16 double-buffered 128-kv chunks. Swapped-operand QK^T: lane holds
// (kv=lg*4+r, q=la). No max-subtraction (logits bounded ~|3|).
// P stores: NT (R7 A/B: NT is +50us vs plain — L2 pollution dominates), and
// register-batched per chunk so adjacent 64B half-lines issue back-to-back
// (R6: interleaved NT half-line stores amplified writes 1.37x).
__global__ __launch_bounds__(512, 4) void attn_fused_k(
    const bf16_t* __restrict__ Qh, const bf16_t* __restrict__ Kh,
    const bf16_t* __restrict__ Vt, const unsigned int* __restrict__ mbits,
    float* __restrict__ P, bf16_t* __restrict__ attn)
{
    __shared__ bf16_t Ks[2][128 * 64];  // 2 x 16 KB swizzled K chunks (dbuf)
    __shared__ bf16_t Pb[8][16 * 128];  // 8 waves x 4 KB bf16 P chunk

    // XCD-bijective swizzle: 512 = 8 XCDs x 64 -> each XCD owns 4 heads
    const int wg = blockIdx.x;
    const int swg = (wg & 7) * 64 + (wg >> 3);
    const int bh = swg >> 4, qs = swg & 15;

    const int tid = threadIdx.x, lane = tid & 63, wv = tid >> 6;  // 8 waves
    const int la = lane & 15, lg = lane >> 4;
    const int b_ = bh >> 4;
    const int qbase = qs * 128 + wv * 16;
    const int swz = (la & 7) << 4;

    bf16x8 qf0, qf1;
    {
        const bf16_t* qrow = Qh + ((size_t)bh * 2048 + qbase + la) * 64 + lg * 8;
        qf0 = *reinterpret_cast<const bf16x8*>(qrow);
        qf1 = *reinterpret_cast<const bf16x8*>(qrow + 32);
    }
    const char* Khb = (const char*)(Kh + ((size_t)bh << 17));
    const bf16_t* Vtb = Vt + ((size_t)bh << 17);
    const unsigned int* mrow = mbits + ((size_t)b_ * 2048 + qbase + la) * 64;
    const float SC = 0.125f * 1.4426950408889634f;

#define STAGE_K(c, bsel)                                                      \
    for (int i = 0; i < 2; ++i) {                                             \
        int o = i * 8192 + tid * 16;                                          \
        int row = o >> 7;                                                     \
        int cb = (o & 127) ^ ((row & 7) << 4);                                \
        load_lds16(Khb + (size_t)(c) * 16384 + row * 128 + cb,                \
                   (char*)Ks[bsel] + i * 8192 + wv * 1024);                   \
    }

    // ---- pass 1: row sums of exp2(logit) ----
    float ssum = 0.f;
    uint4 mws = *reinterpret_cast<const uint4*>(mrow);
    STAGE_K(0, 0)
    __syncthreads();
    for (int c = 0; c < 16; ++c) {
        int cn = (c < 15) ? c + 1 : 15;
        uint4 mnext = *reinterpret_cast<const uint4*>(mrow + cn * 4);  // prefetch
        if (c < 15) { STAGE_K(c + 1, (c + 1) & 1) }
        __builtin_amdgcn_sched_barrier(0);
        const char* Kbase = (const char*)Ks[c & 1];
        unsigned mwarr[4] = {mws.x, mws.y, mws.z, mws.w};
        __builtin_amdgcn_s_setprio(1);
#pragma unroll
        for (int ct = 0; ct < 8; ++ct) {
            int krow = ct * 16 + la;
            const char* kb = Kbase + krow * 128;
            int sw = (krow & 7) << 4;
            bf16x8 kf0 = *reinterpret_cast<const bf16x8*>(kb + ((lg * 16) ^ sw));
            bf16x8 kf1 = *reinterpret_cast<const bf16x8*>(kb + ((64 + lg * 16) ^ sw));
            f32x4 acc = {};
            acc = __builtin_amdgcn_mfma_f32_16x16x32_bf16(kf0, qf0, acc, 0, 0, 0);
            acc = __builtin_amdgcn_mfma_f32_16x16x32_bf16(kf1, qf1, acc, 0, 0, 0);
            unsigned mw = mwarr[ct >> 1];
            int shift = ((ct & 1) << 4) + lg * 4;
            for (int r = 0; r < 4; ++r) {
                float t = __builtin_amdgcn_exp2f(acc[r] * SC);
                ssum += ((mw >> (shift + r)) & 1u) ? t : 0.f;
            }
        }
        __builtin_amdgcn_s_setprio(0);
        __syncthreads();
        mws = mnext;
    }
    // reduce over the 4 lg groups (each lane's q-row = la)
    ssum += __shfl_xor(ssum, 16, 64);
    ssum += __shfl_xor(ssum, 32, 64);
    // v_log_f32 IS log2 -> exp2(x*SC - log2(ssum)) = exp2(x*SC)/ssum
    const float nls = -__builtin_amdgcn_logf(ssum);

    // ---- pass 2: recompute, folded-norm exp2, batched NT P stores, PV ----
    f32x4 accpv[4] = {};
    float* Pq = P + ((size_t)bh << 22) + (size_t)(qbase + la) * 2048;
    char* Pw = (char*)Pb[wv];
    mws = *reinterpret_cast<const uint4*>(mrow);
    STAGE_K(0, 0)
    __syncthreads();
    for (int c = 0; c < 16; ++c) {
        int cn = (c < 15) ? c + 1 : 15;
        uint4 mnext = *reinterpret_cast<const uint4*>(mrow + cn * 4);  // prefetch
        if (c < 15) { STAGE_K(c + 1, (c + 1) & 1) }
        __builtin_amdgcn_sched_barrier(0);
        const char* Kbase = (const char*)Ks[c & 1];
        unsigned mwarr[4] = {mws.x, mws.y, mws.z, mws.w};
        f32x4 pvbuf[8];
        __builtin_amdgcn_s_setprio(1);
#pragma unroll
        for (int ct = 0; ct < 8; ++ct) {
            int krow = ct * 16 + la;
            const char* kb = Kbase + krow * 128;
            int sw = (krow & 7) << 4;
            bf16x8 kf0 = *reinterpret_cast<const bf16x8*>(kb + ((lg * 16) ^ sw));
            bf16x8 kf1 = *reinterpret_cast<const bf16x8*>(kb + ((64 + lg * 16) ^ sw));
            f32x4 acc = {};
            acc = __builtin_amdgcn_mfma_f32_16x16x32_bf16(kf0, qf0, acc, 0, 0, 0);
            acc = __builtin_amdgcn_mfma_f32_16x16x32_bf16(kf1, qf1, acc, 0, 0, 0);
            unsigned mw = mwarr[ct >> 1];
            int shift = ((ct & 1) << 4) + lg * 4;
            f32x4 pv;
            for (int r = 0; r < 4; ++r) {
                float t = __builtin_amdgcn_exp2f(__builtin_fmaf(acc[r], SC, nls));
                pv[r] = ((mw >> (shift + r)) & 1u) ? t : 0.f;
            }
            pvbuf[ct] = pv;
            bf16x4 pb4 = __builtin_convertvector(pv, bf16x4);
            *reinterpret_cast<bf16x4*>(Pw + ((la * 256 + ct * 32 + lg * 8) ^ swz)) = pb4;
        }
        // batched NT stores: adjacent 64B half-lines issue back-to-back so L2
        // sees full 128B lines; they drain under the PV MFMAs below
#pragma unroll
        for (int ct = 0; ct < 8; ++ct)
            __builtin_nontemporal_store(
                pvbuf[ct], reinterpret_cast<f32x4*>(Pq + c * 128 + ct * 16 + lg * 4));
        // per-wave: ensure Pb writes landed before reading A-fragments
        asm volatile("s_waitcnt lgkmcnt(0)" ::: "memory");
        __builtin_amdgcn_sched_barrier(0);
        for (int kbk = 0; kbk < 4; ++kbk) {
            bf16x8 pa = *reinterpret_cast<const bf16x8*>(
                Pw + ((la * 256 + kbk * 64 + lg * 16) ^ swz));
            const bf16_t* vb2 = Vtb + c * 128 + kbk * 32 + lg * 8;
            for (int ni = 0; ni < 4; ++ni) {
                bf16x8 vf = *reinterpret_cast<const bf16x8*>(vb2 + (size_t)(ni * 16 + la) * 2048);
                accpv[ni] = __builtin_amdgcn_mfma_f32_16x16x32_bf16(pa, vf, accpv[ni], 0, 0, 0);
            }
        }
        __builtin_amdgcn_s_setprio(0);
        // counted wait: mask + 2 stage loads are older than the 8 NT stores
        asm volatile("s_waitcnt vmcnt(8)" ::: "memory");
        __builtin_amdgcn_s_barrier();
        mws = mnext;
    }
#undef STAGE_K

    bf16_t* ab = attn + ((size_t)bh << 17);
    for (int ni = 0; ni < 4; ++ni)
        for (int r = 0; r < 4; ++r)
            ab[(size_t)(qbase + lg * 4 + r) * 64 + ni * 16 + la] = (bf16_t)accpv[ni][r];
}

extern "C" void kernel_launch(void* const* d_in, const int* in_sizes, int n_in,
                              void* d_out, int out_size, void* d_ws, size_t ws_size,
                              hipStream_t stream) {
    const float* q  = (const float*)d_in[0];
    const float* k  = (const float*)d_in[1];
    const float* v  = (const float*)d_in[2];
    const int* mask = (const int*)d_in[3];
    const float* Wq = (const float*)d_in[4];
    const float* bq = (const float*)d_in[5];
    const float* Wk = (const float*)d_in[6];
    const float* bk = (const float*)d_in[7];
    const float* Wv = (const float*)d_in[8];
    const float* bv = (const float*)d_in[9];
    const float* Wo = (const float*)d_in[10];
    const float* bo = (const float*)d_in[11];

    char* ws = (char*)d_ws;
    bf16_t* qb    = (bf16_t*)(ws + 0);
    bf16_t* kb    = (bf16_t*)(ws + 8388608);
    bf16_t* vb    = (bf16_t*)(ws + 16777216);
    bf16_t* wqb   = (bf16_t*)(ws + 25165824);
    bf16_t* wkb   = (bf16_t*)(ws + 27262976);
    bf16_t* wvb   = (bf16_t*)(ws + 29360128);
    bf16_t* wob   = (bf16_t*)(ws + 31457280);
    bf16_t* Qh    = (bf16_t*)(ws + 33554432);
    bf16_t* Kh    = (bf16_t*)(ws + 41943040);
    bf16_t* Vt    = (bf16_t*)(ws + 50331648);
    bf16_t* attnb = (bf16_t*)(ws + 58720256);
    unsigned long long* mbits = (unsigned long long*)(ws + 67108864);

    float* out   = (float*)d_out;
    float* score = out + 4194304;

    cvt_all_k<<<dim3(4096, 7), 256, 0, stream>>>(q, k, v, Wq, Wk, Wv, Wo,
                                                 qb, kb, vb, wqb, wkb, wvb, wob);
    pack_mask_k<<<32768, 256, 0, stream>>>(mask, mbits);

    gemm_qkv<<<dim3(32, 8, 3), 256, 0, stream>>>(qb, kb, vb, wqb, wkb, wvb,
                                                 bq, bk, bv, Qh, Kh, Vt);

    attn_fused_k<<<512, 512, 0, stream>>>(Qh, Kh, Vt, (const unsigned int*)mbits,
                                          score, attnb);

    gemm_out<<<dim3(32, 8), 256, 0, stream>>>(attnb, wob, bo, out);
}